// Round 4
// baseline (86.435 us; speedup 1.0000x reference)
//
#include <hip/hip_runtime.h>

// AvgPool2d: x (64, 1024, 1024) f32 -> out (64, 512, 512) f32
// out[b][oy][ox] = mean of 2x2 block at (2*oy, 2*ox).
// Flat output-row index row = b*512 + oy maps to input rows 2*row, 2*row+1
// (H = 1024 = 2*512, so the batch stride collapses into the row index).
//
// One thread computes 8 adjacent outputs: 8x float4 nt loads (4 per input
// row) + 2x float4 nt stores. 160 B in + 32 B out per thread; every byte
// touched exactly once -> nt hints skip cache allocation. 8 loads issued
// back-to-back per thread maximize loads-in-flight per wave.

typedef float vf4 __attribute__((ext_vector_type(4)));

__global__ __launch_bounds__(256) void AvgPool2dLayer_85074712199865_kernel(
    const float* __restrict__ in, float* __restrict__ out, int n_oct) {
    int t = blockIdx.x * blockDim.x + threadIdx.x;
    if (t >= n_oct) return;

    int co  = t & 63;    // octet index within output row (64 octets = 512 cols)
    int row = t >> 6;    // flat output row in [0, 64*512)

    const vf4* r0 = reinterpret_cast<const vf4*>(in + (size_t)(2 * row) * 1024 + (size_t)co * 16);
    const vf4* r1 = reinterpret_cast<const vf4*>(in + (size_t)(2 * row) * 1024 + 1024 + (size_t)co * 16);

    vf4 a0 = __builtin_nontemporal_load(r0);
    vf4 a1 = __builtin_nontemporal_load(r0 + 1);
    vf4 a2 = __builtin_nontemporal_load(r0 + 2);
    vf4 a3 = __builtin_nontemporal_load(r0 + 3);
    vf4 b0 = __builtin_nontemporal_load(r1);
    vf4 b1 = __builtin_nontemporal_load(r1 + 1);
    vf4 b2 = __builtin_nontemporal_load(r1 + 2);
    vf4 b3 = __builtin_nontemporal_load(r1 + 3);

    vf4 o0, o1;
    o0.x = (a0.x + a0.y + b0.x + b0.y) * 0.25f;
    o0.y = (a0.z + a0.w + b0.z + b0.w) * 0.25f;
    o0.z = (a1.x + a1.y + b1.x + b1.y) * 0.25f;
    o0.w = (a1.z + a1.w + b1.z + b1.w) * 0.25f;
    o1.x = (a2.x + a2.y + b2.x + b2.y) * 0.25f;
    o1.y = (a2.z + a2.w + b2.z + b2.w) * 0.25f;
    o1.z = (a3.x + a3.y + b3.x + b3.y) * 0.25f;
    o1.w = (a3.z + a3.w + b3.z + b3.w) * 0.25f;

    vf4* op = reinterpret_cast<vf4*>(out + (size_t)row * 512 + (size_t)co * 8);
    __builtin_nontemporal_store(o0, op);
    __builtin_nontemporal_store(o1, op + 1);
}

extern "C" void kernel_launch(void* const* d_in, const int* in_sizes, int n_in,
                              void* d_out, int out_size, void* d_ws, size_t ws_size,
                              hipStream_t stream) {
    const float* in = (const float*)d_in[0];
    float* out = (float*)d_out;

    const int n_oct = 64 * 512 * 64;  // out_size / 8 = 2,097,152
    const int block = 256;
    const int grid = (n_oct + block - 1) / block;  // 8192 blocks

    AvgPool2dLayer_85074712199865_kernel<<<grid, block, 0, stream>>>(in, out, n_oct);
}

// Round 5
// 58.197 us; speedup vs baseline: 1.4852x; 1.4852x over previous
//
#include <hip/hip_runtime.h>

// AvgPool2d: x (64, 1024, 1024) f32 -> out (64, 512, 512) f32
// out[b][oy][ox] = mean of 2x2 block at (2*oy, 2*ox).
// Flat output row = b*512 + oy; input rows 2*row, 2*row+1 (batch collapses).
//
// R4 lesson: widening the per-thread contiguous chunk breaks per-instruction
// coalescing (lanes stride apart). Instead: block of 256 threads owns 4 flat
// output rows = 8 contiguous input rows (32 KB). Thread t loads vf4 at
// row_k*1024 + t*4 for k=0..7 -> every load instruction is 256x16B = 4 KB
// dense. Row pair (2j, 2j+1) combines within the same thread into a float2
// store at out_row_j*512 + t*2 -> every store is 2 KB dense. nt hints are
// safe again: each fetched line is fully consumed by a single instruction.

typedef float vf4 __attribute__((ext_vector_type(4)));
typedef float vf2 __attribute__((ext_vector_type(2)));

__global__ __launch_bounds__(256) void AvgPool2dLayer_85074712199865_kernel(
    const float* __restrict__ in, float* __restrict__ out) {
    const int t = threadIdx.x;
    const size_t orow0 = (size_t)blockIdx.x * 4;   // first flat output row of this block

    const float* ip = in + orow0 * 2048 + (size_t)t * 4;  // input base (2*orow0 rows of 1024)

    // 8 fully-coalesced nt loads, issued back-to-back (8 in flight).
    vf4 a0 = __builtin_nontemporal_load(reinterpret_cast<const vf4*>(ip + 0 * 1024));
    vf4 a1 = __builtin_nontemporal_load(reinterpret_cast<const vf4*>(ip + 1 * 1024));
    vf4 a2 = __builtin_nontemporal_load(reinterpret_cast<const vf4*>(ip + 2 * 1024));
    vf4 a3 = __builtin_nontemporal_load(reinterpret_cast<const vf4*>(ip + 3 * 1024));
    vf4 a4 = __builtin_nontemporal_load(reinterpret_cast<const vf4*>(ip + 4 * 1024));
    vf4 a5 = __builtin_nontemporal_load(reinterpret_cast<const vf4*>(ip + 5 * 1024));
    vf4 a6 = __builtin_nontemporal_load(reinterpret_cast<const vf4*>(ip + 6 * 1024));
    vf4 a7 = __builtin_nontemporal_load(reinterpret_cast<const vf4*>(ip + 7 * 1024));

    // Horizontal pair-sums: row k contributes to output cols (2t, 2t+1).
    vf2 o0, o1, o2, o3;
    o0.x = (a0.x + a0.y + a1.x + a1.y) * 0.25f;
    o0.y = (a0.z + a0.w + a1.z + a1.w) * 0.25f;
    o1.x = (a2.x + a2.y + a3.x + a3.y) * 0.25f;
    o1.y = (a2.z + a2.w + a3.z + a3.w) * 0.25f;
    o2.x = (a4.x + a4.y + a5.x + a5.y) * 0.25f;
    o2.y = (a4.z + a4.w + a5.z + a5.w) * 0.25f;
    o3.x = (a6.x + a6.y + a7.x + a7.y) * 0.25f;
    o3.y = (a6.z + a6.w + a7.z + a7.w) * 0.25f;

    float* op = out + orow0 * 512 + (size_t)t * 2;
    __builtin_nontemporal_store(o0, reinterpret_cast<vf2*>(op + 0 * 512));
    __builtin_nontemporal_store(o1, reinterpret_cast<vf2*>(op + 1 * 512));
    __builtin_nontemporal_store(o2, reinterpret_cast<vf2*>(op + 2 * 512));
    __builtin_nontemporal_store(o3, reinterpret_cast<vf2*>(op + 3 * 512));
}

extern "C" void kernel_launch(void* const* d_in, const int* in_sizes, int n_in,
                              void* d_out, int out_size, void* d_ws, size_t ws_size,
                              hipStream_t stream) {
    const float* in = (const float*)d_in[0];
    float* out = (float*)d_out;

    const int grid = 64 * 512 / 4;  // 8192 blocks, 4 flat output rows each

    AvgPool2dLayer_85074712199865_kernel<<<grid, 256, 0, stream>>>(in, out);
}

// Round 6
// 57.539 us; speedup vs baseline: 1.5022x; 1.0114x over previous
//
#include <hip/hip_runtime.h>

// AvgPool2d: x (64, 1024, 1024) f32 -> out (64, 512, 512) f32
// out[b][oy][ox] = mean of 2x2 block at (2*oy, 2*ox).
// Flat output row = b*512 + oy; input rows 2*row, 2*row+1 (batch collapses).
//
// R5 structure (proved fully-coalesced, exactly-once traffic) + persistent
// grid-stride: 2048 blocks (256 CU x 8 waves of blocks), each loops over 4
// tiles. Each tile: block owns 4 flat output rows = 8 contiguous input rows;
// thread t does 8x vf4 nt loads (each instruction 256x16B = 4 KB dense) and
// 4x vf2 nt stores (2 KB dense). Loop overlaps next tile's loads with
// current tile's store drain and removes the 8192-block dispatch ramp/tail.

typedef float vf4 __attribute__((ext_vector_type(4)));
typedef float vf2 __attribute__((ext_vector_type(2)));

#define NBLOCKS 2048
#define NTILES  8192   // 64*512/4 flat-output-row groups of 4

__global__ __launch_bounds__(256) void AvgPool2dLayer_85074712199865_kernel(
    const float* __restrict__ in, float* __restrict__ out) {
    const int t = threadIdx.x;

    #pragma unroll 1
    for (int tile = blockIdx.x; tile < NTILES; tile += NBLOCKS) {
        const size_t orow0 = (size_t)tile * 4;            // first flat output row
        const float* ip = in + orow0 * 2048 + (size_t)t * 4;

        vf4 a0 = __builtin_nontemporal_load(reinterpret_cast<const vf4*>(ip + 0 * 1024));
        vf4 a1 = __builtin_nontemporal_load(reinterpret_cast<const vf4*>(ip + 1 * 1024));
        vf4 a2 = __builtin_nontemporal_load(reinterpret_cast<const vf4*>(ip + 2 * 1024));
        vf4 a3 = __builtin_nontemporal_load(reinterpret_cast<const vf4*>(ip + 3 * 1024));
        vf4 a4 = __builtin_nontemporal_load(reinterpret_cast<const vf4*>(ip + 4 * 1024));
        vf4 a5 = __builtin_nontemporal_load(reinterpret_cast<const vf4*>(ip + 5 * 1024));
        vf4 a6 = __builtin_nontemporal_load(reinterpret_cast<const vf4*>(ip + 6 * 1024));
        vf4 a7 = __builtin_nontemporal_load(reinterpret_cast<const vf4*>(ip + 7 * 1024));

        vf2 o0, o1, o2, o3;
        o0.x = (a0.x + a0.y + a1.x + a1.y) * 0.25f;
        o0.y = (a0.z + a0.w + a1.z + a1.w) * 0.25f;
        o1.x = (a2.x + a2.y + a3.x + a3.y) * 0.25f;
        o1.y = (a2.z + a2.w + a3.z + a3.w) * 0.25f;
        o2.x = (a4.x + a4.y + a5.x + a5.y) * 0.25f;
        o2.y = (a4.z + a4.w + a5.z + a5.w) * 0.25f;
        o3.x = (a6.x + a6.y + a7.x + a7.y) * 0.25f;
        o3.y = (a6.z + a6.w + a7.z + a7.w) * 0.25f;

        float* op = out + orow0 * 512 + (size_t)t * 2;
        __builtin_nontemporal_store(o0, reinterpret_cast<vf2*>(op + 0 * 512));
        __builtin_nontemporal_store(o1, reinterpret_cast<vf2*>(op + 1 * 512));
        __builtin_nontemporal_store(o2, reinterpret_cast<vf2*>(op + 2 * 512));
        __builtin_nontemporal_store(o3, reinterpret_cast<vf2*>(op + 3 * 512));
    }
}

extern "C" void kernel_launch(void* const* d_in, const int* in_sizes, int n_in,
                              void* d_out, int out_size, void* d_ws, size_t ws_size,
                              hipStream_t stream) {
    const float* in = (const float*)d_in[0];
    float* out = (float*)d_out;

    AvgPool2dLayer_85074712199865_kernel<<<NBLOCKS, 256, 0, stream>>>(in, out);
}